// Round 7
// baseline (9370.911 us; speedup 1.0000x reference)
//
#include <hip/hip_runtime.h>

// R7: fused serial recurrences + feed-forward offload.
//  - 32 blocks x 512 thr. Blocks 0..15 ("fused", group g=blockIdx): BOTH
//    recurrences, one barrier/step, L1 lagged 2: iter k does L0(k) and L1(k-2).
//    Only recurrent weights in regs (Whh0+Whh1 = 128 VGPR) -> no spills.
//  - Blocks 16..31 ("helper", same g): feed-forward GEMMs
//      zx(t) = s*(Wih0 x(t) + b0)   (pure feed-forward, lookahead LA=2)
//      z1(t) = s*(Wih1 h0(t) + b1)  (lags h0 by design)
//    streamed as f32 D-fragment images through d_ws rings. Cross-CU protocol
//    latency lands on paths with >=2 steps of slack, never on the h0/h1 chain.
//  - Flags monotone, zeroed per launch; skew locked to [0,2] by the zf wait.
//  - Fallback: proven R2 single-kernel path if ws too small.

typedef short bf16x8 __attribute__((ext_vector_type(8)));
typedef float f32x4 __attribute__((ext_vector_type(4)));
typedef unsigned long long ull;

static constexpr int CIN = 12, T = 2048, H = 128;
static constexpr int NTHR = 512;
static constexpr float L2E = 1.4426950408889634f;

static constexpr int HR = 4, ZXR = 4, ZR = 4;       // ring slots
static constexpr size_t H0SLOT = 4096;              // 16b x 128 x bf16
static constexpr size_t ZSLOT  = 32768;             // 512 rows x 16b x f32
static constexpr size_t ZXOFF  = HR * H0SLOT;                 // 16384
static constexpr size_t Z1OFF  = ZXOFF + ZXR * ZSLOT;         // 147456
static constexpr size_t GRB    = Z1OFF + ZR * ZSLOT;          // 278528
static constexpr size_t FLAG_BYTES = 8192;
static constexpr size_t WS_NEED = FLAG_BYTES + 16ull * GRB;   // ~4.26 MB

#if __has_builtin(__builtin_amdgcn_exp2f)
#define EXP2(x) __builtin_amdgcn_exp2f(x)
#else
#define EXP2(x) exp2f(x)
#endif

__device__ __forceinline__ unsigned f2bf(float f) {  // f32 -> bf16 bits, RTNE
  unsigned u = __builtin_bit_cast(unsigned, f);
  return (u + 0x7FFFu + ((u >> 16) & 1u)) >> 16;
}

__device__ __forceinline__ unsigned cvtpk_bf16(float lo, float hi) {
  unsigned r;
  asm("v_cvt_pk_bf16_f32 %0, %1, %2" : "=v"(r) : "v"(lo), "v"(hi));
  return r;
}

__device__ __forceinline__ float sig_pre(float a) {  // 1/(1+2^a)
  return __builtin_amdgcn_rcpf(1.f + EXP2(a));
}

__device__ __forceinline__ ull lstm_ew(
    const f32x4& a0, const f32x4& a1, const f32x4& a2, const f32x4& a3,
    float* cv, float* hv) {
  #pragma unroll
  for (int r = 0; r < 4; ++r) {
    const float iv = sig_pre(a0[r]);
    const float fv = sig_pre(a1[r]);
    const float gv = fmaf(-2.f, sig_pre(a2[r]), 1.f);
    const float ov = sig_pre(a3[r]);
    const float c  = fmaf(fv, cv[r], iv * gv);
    cv[r] = c;
    const float th = fmaf(-2.f, sig_pre(c * (2.f * L2E)), 1.f);
    hv[r] = ov * th;
  }
  const unsigned hp0 = cvtpk_bf16(hv[0], hv[1]);
  const unsigned hp1 = cvtpk_bf16(hv[2], hv[3]);
  return ((ull)hp1 << 32) | hp0;
}

__device__ __forceinline__ void wait_ge(unsigned* p, unsigned tgt) {
  while (__hip_atomic_load(p, __ATOMIC_ACQUIRE, __HIP_MEMORY_SCOPE_AGENT) < tgt)
    __builtin_amdgcn_s_sleep(1);
}

__global__ void lstm_zero_flags(unsigned* f) {
  f[blockIdx.x * 256 + threadIdx.x] = 0;  // 8 blocks x 256 = 8KB
}

// ============================ main kernel ============================
__global__ __launch_bounds__(NTHR, 2) void lstm_fz(
    const float* __restrict__ xg,
    const float* __restrict__ Wih0, const float* __restrict__ Whh0,
    const float* __restrict__ bih0, const float* __restrict__ bhh0,
    const float* __restrict__ Wih1, const float* __restrict__ Whh1,
    const float* __restrict__ bih1, const float* __restrict__ bhh1,
    const float* __restrict__ Wd,   const float* __restrict__ bd,
    float* __restrict__ out, char* __restrict__ ws)
{
  __shared__ char lds[18432];
  const int tid = threadIdx.x;
  const int l  = tid & 63;
  const int w  = tid >> 6;   // wave 0..7
  const int lg = l >> 4;     // lane group 0..3
  const int lr = l & 15;     // A: row-in-tile ; B/D: batch column
  const int g  = blockIdx.x & 15;

  unsigned* h0f = (unsigned*)ws + g * 64;          // 256B stride
  unsigned* zf  = (unsigned*)ws + 1024 + g * 64;
  char* grb    = ws + FLAG_BYTES + (size_t)g * GRB;
  char* h0ring = grb;
  char* zxring = grb + ZXOFF;
  char* z1ring = grb + Z1OFF;

  const int rdB  = lg * 256 + lr * 16;             // B-frag read base
  const int bcol = w * 16 + lg * 4;                // base h-column (4/lane)
  const int wrH  = (bcol >> 3) * 256 + lr * 16 + (bcol & 7) * 2;
  const int zoff = tid * 16;                       // f32x4 per lane per q-plane

  if (blockIdx.x >= 16) {
    // ---------------- HELPER: zx (lookahead 2) + z1 (lag behind h0) ----------------
    for (int i = tid; i < 2048 / 4; i += NTHR) ((int*)lds)[i] = 0;  // X 2 slots
    __syncthreads();
    if (tid < 32) {  // const-1.0 at k==12 (pairs with b0 column in A0x)
      const int buf = tid >> 4, b = tid & 15;
      *(unsigned short*)(lds + buf * 1024 + 256 + b * 16 + 8) = 0x3F80;
    }

    bf16x8 Aih[4][4], A0x[4];
    f32x4 b1r[4];
    #pragma unroll
    for (int q = 0; q < 4; ++q) {
      const int n = (q * 8 + w) * 16 + lr;
      const float s = (q == 2) ? (2.f * L2E) : (-L2E);
      #pragma unroll
      for (int kf = 0; kf < 4; ++kf) {
        const float* src = &Wih1[n * H + kf * 32 + lg * 8];
        #pragma unroll
        for (int j = 0; j < 8; ++j) Aih[q][kf][j] = (short)f2bf(src[j] * s);
      }
      #pragma unroll
      for (int j = 0; j < 8; ++j) {
        const int k = lg * 8 + j;
        float v = 0.f;
        if (k < CIN) v = Wih0[n * CIN + k] * s;
        else if (k == CIN) v = (bih0[n] + bhh0[n]) * s;
        A0x[q][j] = (short)f2bf(v);
      }
      #pragma unroll
      for (int r = 0; r < 4; ++r) {
        const int nd = (q * 8 + w) * 16 + lg * 4 + r;
        b1r[q][r] = (bih1[nd] + bhh1[nd]) * s;
      }
    }
    const f32x4 zed = {0.f, 0.f, 0.f, 0.f};

    const int xb = tid & 15, xc = tid >> 4;
    const bool ldx = (tid < 192);
    const int wrX = (xc >> 3) * 256 + xb * 16 + (xc & 7) * 2;
    const size_t xbase = (size_t)(g * 16 + xb) * (CIN * T) + (size_t)xc * T;

    // prologue: zx(0), zx(1)
    if (ldx) {
      *(unsigned short*)(lds + wrX)        = (unsigned short)f2bf(xg[xbase + 0]);
      *(unsigned short*)(lds + 1024 + wrX) = (unsigned short)f2bf(xg[xbase + 1]);
    }
    __syncthreads();
    #pragma unroll
    for (int m = 0; m < 2; ++m) {
      const bf16x8 bx = *(const bf16x8*)(lds + m * 1024 + rdB);
      char* d = zxring + (size_t)m * ZSLOT;
      #pragma unroll
      for (int q = 0; q < 4; ++q) {
        f32x4 ax = __builtin_amdgcn_mfma_f32_16x16x32_bf16(A0x[q], bx, zed, 0, 0, 0);
        *(f32x4*)(d + q * 8192 + zoff) = ax;
      }
    }
    __syncthreads();  // drains stores (each thread's vmcnt) before flag
    if (tid == 0)
      __hip_atomic_store(zf, 2u, __ATOMIC_RELEASE, __HIP_MEMORY_SCOPE_AGENT);

    unsigned hseen = 0;
    for (int j = 0; j < T; ++j) {
      const bool hasx = (j + 2 < T);
      float xv = 0.f;
      if (hasx && ldx) xv = xg[xbase + j + 2];
      if (hseen < (unsigned)(j + 1)) { wait_ge(h0f, (unsigned)(j + 1)); hseen = (unsigned)(j + 1); }
      const char* hs = h0ring + (size_t)(j & (HR - 1)) * H0SLOT;
      bf16x8 hf[4];
      #pragma unroll
      for (int kf = 0; kf < 4; ++kf)
        hf[kf] = *(const bf16x8*)(hs + kf * 1024 + rdB);
      if (hasx && ldx)
        *(unsigned short*)(lds + (j & 1) * 1024 + wrX) = (unsigned short)f2bf(xv);
      __syncthreads();
      if (hasx) {
        const bf16x8 bx = *(const bf16x8*)(lds + (j & 1) * 1024 + rdB);
        char* d = zxring + (size_t)((j + 2) & (ZXR - 1)) * ZSLOT;
        #pragma unroll
        for (int q = 0; q < 4; ++q) {
          f32x4 ax = __builtin_amdgcn_mfma_f32_16x16x32_bf16(A0x[q], bx, zed, 0, 0, 0);
          *(f32x4*)(d + q * 8192 + zoff) = ax;
        }
      }
      {
        char* d = z1ring + (size_t)(j & (ZR - 1)) * ZSLOT;
        #pragma unroll
        for (int q = 0; q < 4; ++q) {
          f32x4 az = b1r[q];
          #pragma unroll
          for (int kf = 0; kf < 4; ++kf)
            az = __builtin_amdgcn_mfma_f32_16x16x32_bf16(Aih[q][kf], hf[kf], az, 0, 0, 0);
          *(f32x4*)(d + q * 8192 + zoff) = az;
        }
      }
      __syncthreads();
      if (tid == 0)
        __hip_atomic_store(zf, (unsigned)(j + 3), __ATOMIC_RELEASE, __HIP_MEMORY_SCOPE_AGENT);
    }
    return;
  }

  // ---------------- FUSED: L0(k) + L1(k-2), one barrier/step ----------------
  // LDS: H0 dbuf @0 (2x4096), H1 dbuf @8192 (2x4096), RED @16384 (2KB)
  for (int i = tid; i < 18432 / 4; i += NTHR) ((int*)lds)[i] = 0;

  bf16x8 Ah0[4][4], Ah1[4][4];
  #pragma unroll
  for (int q = 0; q < 4; ++q) {
    const int n = (q * 8 + w) * 16 + lr;
    const float s = (q == 2) ? (2.f * L2E) : (-L2E);
    #pragma unroll
    for (int kf = 0; kf < 4; ++kf) {
      const float* s0 = &Whh0[n * H + kf * 32 + lg * 8];
      const float* s1 = &Whh1[n * H + kf * 32 + lg * 8];
      #pragma unroll
      for (int j = 0; j < 8; ++j) {
        Ah0[q][kf][j] = (short)f2bf(s0[j] * s);
        Ah1[q][kf][j] = (short)f2bf(s1[j] * s);
      }
    }
  }
  __syncthreads();

  float c0v[4] = {0.f, 0.f, 0.f, 0.f};
  float c1v[4] = {0.f, 0.f, 0.f, 0.f};
  float h1v[4] = {0.f, 0.f, 0.f, 0.f};
  float h0t[4];
  unsigned zseen = 0;

  // pre-iters k=0,1: L0 only
  for (int k = 0; k < 2; ++k) {
    const int p = k & 1;
    if (zseen < (unsigned)(k + 1)) { wait_ge(zf, (unsigned)(k + 1)); zseen = (unsigned)(k + 1); }
    const char* zxs = zxring + (size_t)(k & (ZXR - 1)) * ZSLOT;
    f32x4 accA[4];
    #pragma unroll
    for (int q = 0; q < 4; ++q) accA[q] = *(const f32x4*)(zxs + q * 8192 + zoff);
    bf16x8 b0f[4];
    #pragma unroll
    for (int kf = 0; kf < 4; ++kf)
      b0f[kf] = *(const bf16x8*)(lds + p * 4096 + kf * 1024 + rdB);
    #pragma unroll
    for (int kf = 0; kf < 4; ++kf)
      #pragma unroll
      for (int q = 0; q < 4; ++q)
        accA[q] = __builtin_amdgcn_mfma_f32_16x16x32_bf16(Ah0[q][kf], b0f[kf], accA[q], 0, 0, 0);
    const ull hv = lstm_ew(accA[0], accA[1], accA[2], accA[3], c0v, h0t);
    *(ull*)(lds + (1 - p) * 4096 + wrH) = hv;
    *(ull*)(h0ring + (size_t)(k & (HR - 1)) * H0SLOT + wrH) = hv;
    __syncthreads();
    if (tid == 0)
      __hip_atomic_store(h0f, (unsigned)(k + 1), __ATOMIC_RELEASE, __HIP_MEMORY_SCOPE_AGENT);
  }

  // main loop k=2..T-1: L0(k) + L1(k-2)
  #pragma unroll 2
  for (int k = 2; k < T; ++k) {
    const int p = k & 1;
    if (zseen < (unsigned)(k + 1)) { wait_ge(zf, (unsigned)(k + 1)); zseen = (unsigned)(k + 1); }
    const char* zxs = zxring + (size_t)(k & (ZXR - 1)) * ZSLOT;
    const char* z1s = z1ring + (size_t)((k - 2) & (ZR - 1)) * ZSLOT;
    f32x4 accA[4], accB[4];
    #pragma unroll
    for (int q = 0; q < 4; ++q) {
      accA[q] = *(const f32x4*)(zxs + q * 8192 + zoff);
      accB[q] = *(const f32x4*)(z1s + q * 8192 + zoff);
    }
    bf16x8 b0f[4], b1f[4];
    #pragma unroll
    for (int kf = 0; kf < 4; ++kf) {
      b0f[kf] = *(const bf16x8*)(lds + p * 4096 + kf * 1024 + rdB);
      b1f[kf] = *(const bf16x8*)(lds + 8192 + p * 4096 + kf * 1024 + rdB);
    }
    #pragma unroll
    for (int kf = 0; kf < 4; ++kf)
      #pragma unroll
      for (int q = 0; q < 4; ++q) {
        accA[q] = __builtin_amdgcn_mfma_f32_16x16x32_bf16(Ah0[q][kf], b0f[kf], accA[q], 0, 0, 0);
        accB[q] = __builtin_amdgcn_mfma_f32_16x16x32_bf16(Ah1[q][kf], b1f[kf], accB[q], 0, 0, 0);
      }
    const ull hvA = lstm_ew(accA[0], accA[1], accA[2], accA[3], c0v, h0t);
    *(ull*)(lds + (1 - p) * 4096 + wrH) = hvA;
    *(ull*)(h0ring + (size_t)(k & (HR - 1)) * H0SLOT + wrH) = hvA;
    const ull hvB = lstm_ew(accB[0], accB[1], accB[2], accB[3], c1v, h1v);
    *(ull*)(lds + 8192 + (1 - p) * 4096 + wrH) = hvB;
    __syncthreads();
    if (tid == 0)
      __hip_atomic_store(h0f, (unsigned)(k + 1), __ATOMIC_RELEASE, __HIP_MEMORY_SCOPE_AGENT);
  }

  // peel A: h1(T-2)  (h1(T-3) sits in H1[0] after the loop; T even)
  {
    wait_ge(zf, (unsigned)(T + 1));
    const char* z1s = z1ring + (size_t)((T - 2) & (ZR - 1)) * ZSLOT;
    f32x4 accB[4];
    #pragma unroll
    for (int q = 0; q < 4; ++q) accB[q] = *(const f32x4*)(z1s + q * 8192 + zoff);
    bf16x8 b1f[4];
    #pragma unroll
    for (int kf = 0; kf < 4; ++kf)
      b1f[kf] = *(const bf16x8*)(lds + 8192 + kf * 1024 + rdB);
    #pragma unroll
    for (int kf = 0; kf < 4; ++kf)
      #pragma unroll
      for (int q = 0; q < 4; ++q)
        accB[q] = __builtin_amdgcn_mfma_f32_16x16x32_bf16(Ah1[q][kf], b1f[kf], accB[q], 0, 0, 0);
    const ull hvB = lstm_ew(accB[0], accB[1], accB[2], accB[3], c1v, h1v);
    *(ull*)(lds + 8192 + 4096 + wrH) = hvB;
    __syncthreads();
  }
  // peel B: h1(T-1)
  {
    wait_ge(zf, (unsigned)(T + 2));
    const char* z1s = z1ring + (size_t)((T - 1) & (ZR - 1)) * ZSLOT;
    f32x4 accB[4];
    #pragma unroll
    for (int q = 0; q < 4; ++q) accB[q] = *(const f32x4*)(z1s + q * 8192 + zoff);
    bf16x8 b1f[4];
    #pragma unroll
    for (int kf = 0; kf < 4; ++kf)
      b1f[kf] = *(const bf16x8*)(lds + 8192 + 4096 + kf * 1024 + rdB);
    #pragma unroll
    for (int kf = 0; kf < 4; ++kf)
      #pragma unroll
      for (int q = 0; q < 4; ++q)
        accB[q] = __builtin_amdgcn_mfma_f32_16x16x32_bf16(Ah1[q][kf], b1f[kf], accB[q], 0, 0, 0);
    lstm_ew(accB[0], accB[1], accB[2], accB[3], c1v, h1v);
  }

  // ---- epilogue: feats = h1(T-1), scores = sigmoid(h1 . Wd + bd) ----
  const float4 wd = *(const float4*)&Wd[bcol];
  const float partial = h1v[0] * wd.x + h1v[1] * wd.y + h1v[2] * wd.z + h1v[3] * wd.w;
  #pragma unroll
  for (int r = 0; r < 4; ++r)
    out[256 + (size_t)(g * 16 + lr) * H + (bcol + r)] = h1v[r];
  ((float*)(lds + 16384))[tid] = partial;
  __syncthreads();
  if (tid < 16) {
    float s = 0.f;
    #pragma unroll 8
    for (int k = 0; k < 32; ++k) s += ((float*)(lds + 16384))[tid + 16 * k];
    out[g * 16 + tid] = __builtin_amdgcn_rcpf(1.f + EXP2(-(s + bd[0]) * L2E));
  }
}

// ============================ fallback: R2 single kernel ============================
__global__ __launch_bounds__(NTHR, 2) void lstm_single(
    const float* __restrict__ xg,
    const float* __restrict__ Wih0, const float* __restrict__ Whh0,
    const float* __restrict__ bih0, const float* __restrict__ bhh0,
    const float* __restrict__ Wih1, const float* __restrict__ Whh1,
    const float* __restrict__ bih1, const float* __restrict__ bhh1,
    const float* __restrict__ Wd,   const float* __restrict__ bd,
    float* __restrict__ out)
{
  constexpr int LDS_H0 = 0, LDS_H1 = 8192, LDS_X = 16384, LDS_RED = 18432, LDS_SZ = 20480;
  __shared__ char lds[LDS_SZ];
  const int tid = threadIdx.x;
  const int l  = tid & 63;
  const int w  = tid >> 6;
  const int lg = l >> 4;
  const int lr = l & 15;
  const int b0 = blockIdx.x * 16;

  for (int i = tid; i < LDS_SZ / 4; i += NTHR) ((int*)lds)[i] = 0;
  __syncthreads();
  if (tid < 32) {
    const int buf = tid >> 4, b = tid & 15;
    *(unsigned short*)(lds + LDS_X + buf * 1024 + 256 + b * 16 + 8) = 0x3F80;
  }

  bf16x8 A0[4][5];
  bf16x8 A1[4][8];
  f32x4 b1r[4];
  #pragma unroll
  for (int q = 0; q < 4; ++q) {
    const int n = (q * 8 + w) * 16 + lr;
    const float s = (q == 2) ? (2.f * L2E) : (-L2E);
    #pragma unroll
    for (int kf = 0; kf < 4; ++kf) {
      const float* src = &Whh0[n * H + kf * 32 + lg * 8];
      #pragma unroll
      for (int j = 0; j < 8; ++j) A0[q][kf][j] = (short)f2bf(src[j] * s);
    }
    #pragma unroll
    for (int j = 0; j < 8; ++j) {
      const int k = lg * 8 + j;
      float v = 0.f;
      if (k < CIN) v = Wih0[n * CIN + k] * s;
      else if (k == CIN) v = (bih0[n] + bhh0[n]) * s;
      A0[q][4][j] = (short)f2bf(v);
    }
    #pragma unroll
    for (int kf = 0; kf < 4; ++kf) {
      const float* srcA = &Whh1[n * H + kf * 32 + lg * 8];
      const float* srcB = &Wih1[n * H + kf * 32 + lg * 8];
      #pragma unroll
      for (int j = 0; j < 8; ++j) {
        A1[q][kf][j]     = (short)f2bf(srcA[j] * s);
        A1[q][4 + kf][j] = (short)f2bf(srcB[j] * s);
      }
    }
    #pragma unroll
    for (int r = 0; r < 4; ++r) {
      const int nd = (q * 8 + w) * 16 + lg * 4 + r;
      b1r[q][r] = (bih1[nd] + bhh1[nd]) * s;
    }
  }
  const f32x4 zed = {0.f, 0.f, 0.f, 0.f};

  const int rdB  = lg * 256 + lr * 16;
  const int bcol = w * 16 + lg * 4;
  const int wrH  = (bcol >> 3) * 256 + lr * 16 + (bcol & 7) * 2;
  const int xb = tid & 15, xc = tid >> 4;
  const int wrX = (xc >> 3) * 256 + xb * 16 + (xc & 7) * 2;
  const size_t xbase = (size_t)(b0 + xb) * (CIN * T) + (size_t)xc * T;

  if (tid < 192)
    *(unsigned short*)(lds + LDS_X + wrX) = (unsigned short)f2bf(xg[xbase]);
  __syncthreads();

  float c0v[4] = {0.f, 0.f, 0.f, 0.f};
  float c1v[4] = {0.f, 0.f, 0.f, 0.f};
  float h1v[4] = {0.f, 0.f, 0.f, 0.f};
  float h0t[4];

  #pragma unroll 2
  for (int t = 0; t < T; ++t) {
    const int p = t & 1;
    float xnext = 0.f;
    if (tid < 192) xnext = xg[xbase + (t + 1 < T ? t + 1 : t)];

    f32x4 acc[4];
    #pragma unroll
    for (int q = 0; q < 4; ++q) acc[q] = zed;
    #pragma unroll
    for (int kf = 0; kf < 5; ++kf) {
      const int src = (kf < 4) ? (LDS_H0 + p * 4096 + kf * 1024 + rdB)
                               : (LDS_X + p * 1024 + rdB);
      const bf16x8 bf = *(const bf16x8*)(lds + src);
      #pragma unroll
      for (int q = 0; q < 4; ++q)
        acc[q] = __builtin_amdgcn_mfma_f32_16x16x32_bf16(A0[q][kf], bf, acc[q], 0, 0, 0);
    }
    *(ull*)(lds + LDS_H0 + (1 - p) * 4096 + wrH) =
        lstm_ew(acc[0], acc[1], acc[2], acc[3], c0v, h0t);
    if (tid < 192) {
      const unsigned xp = cvtpk_bf16(xnext, xnext);
      *(unsigned short*)(lds + LDS_X + (1 - p) * 1024 + wrX) = (unsigned short)xp;
    }
    __syncthreads();

    #pragma unroll
    for (int q = 0; q < 4; ++q) acc[q] = b1r[q];
    #pragma unroll
    for (int kf = 0; kf < 8; ++kf) {
      const int src = (kf < 4)
          ? (LDS_H1 + p * 4096 + kf * 1024 + rdB)
          : (LDS_H0 + (1 - p) * 4096 + (kf - 4) * 1024 + rdB);
      const bf16x8 bf = *(const bf16x8*)(lds + src);
      #pragma unroll
      for (int q = 0; q < 4; ++q)
        acc[q] = __builtin_amdgcn_mfma_f32_16x16x32_bf16(A1[q][kf], bf, acc[q], 0, 0, 0);
    }
    *(ull*)(lds + LDS_H1 + (1 - p) * 4096 + wrH) =
        lstm_ew(acc[0], acc[1], acc[2], acc[3], c1v, h1v);
    __syncthreads();
  }

  const float4 wd = *(const float4*)&Wd[bcol];
  const float partial = h1v[0] * wd.x + h1v[1] * wd.y + h1v[2] * wd.z + h1v[3] * wd.w;
  #pragma unroll
  for (int r = 0; r < 4; ++r)
    out[256 + (size_t)(b0 + lr) * H + (bcol + r)] = h1v[r];
  ((float*)(lds + LDS_RED))[tid] = partial;
  __syncthreads();
  if (tid < 16) {
    float s = 0.f;
    #pragma unroll 8
    for (int k = 0; k < 32; ++k) s += ((float*)(lds + LDS_RED))[tid + 16 * k];
    const float v = s + bd[0];
    out[b0 + tid] = __builtin_amdgcn_rcpf(1.f + EXP2(-v * L2E));
  }
}

extern "C" void kernel_launch(void* const* d_in, const int* in_sizes, int n_in,
                              void* d_out, int out_size, void* d_ws, size_t ws_size,
                              hipStream_t stream) {
  const float* x    = (const float*)d_in[0];
  // d_in[1] = seq_lengths : unused by the reference
  const float* Wih0 = (const float*)d_in[2];
  const float* Whh0 = (const float*)d_in[3];
  const float* bih0 = (const float*)d_in[4];
  const float* bhh0 = (const float*)d_in[5];
  const float* Wih1 = (const float*)d_in[6];
  const float* Whh1 = (const float*)d_in[7];
  const float* bih1 = (const float*)d_in[8];
  const float* bhh1 = (const float*)d_in[9];
  const float* Wd   = (const float*)d_in[10];
  const float* bd   = (const float*)d_in[11];
  (void)in_sizes; (void)n_in; (void)out_size;

  if (ws_size >= WS_NEED && d_ws != nullptr) {
    lstm_zero_flags<<<dim3(8), dim3(256), 0, stream>>>((unsigned*)d_ws);
    lstm_fz<<<dim3(32), dim3(NTHR), 0, stream>>>(
        x, Wih0, Whh0, bih0, bhh0, Wih1, Whh1, bih1, bhh1, Wd, bd,
        (float*)d_out, (char*)d_ws);
  } else {
    lstm_single<<<dim3(16), dim3(NTHR), 0, stream>>>(
        x, Wih0, Whh0, bih0, bhh0, Wih1, Whh1, bih1, bhh1, Wd, bd, (float*)d_out);
  }
}